// Round 23
// baseline (233.370 us; speedup 1.0000x reference)
//
#include <hip/hip_runtime.h>
#include <hip/hip_bf16.h>
#include <math.h>

// Problem constants: B=2,T=8,D=64,H=64,W=64,D2=128,E=4,HID=256
// token index = ((bt)*64 + h)*64 + w ; bt = b*8+t ; NTOK = 65536

// -------- workspace layout (float offsets) --------
// xcl BF16 at ws+0: re elems [0,4.19M), im [4.19M,8.39M) -> floats [0, 4194304)
#define W_XB     4194304u     // xclbase BF16 (input, [bt][d][h][w] layout): floats [4.19M, 8.39M)
#define W_C      8388608u     // xn BF16 [tok][128]; LIVE through k3_conv_enc (fused GEMM!)
#define W_CWT    12582912u    // bf16 conv weights, fragment order [9][8][4][64][8]
#define W_W1T    14680064u    // bf16 w1 FRAGMENT order [4][16 nt][4 kt][64][8]
#define W_W2T    14745600u    // bf16 w2 FRAGMENT order [4][8 nt][8 kt][64][8]
#define W_ENCM   14811136u    // bf16 enc cat-matrix frag order
#define W_DECM   14819328u    // bf16 dec cat-matrix frag order -> ends 14827520
#define W_XMP_RE 14827520u    // x_mean partials [1024 blk][64]
#define W_XMP_IM 14893056u
#define W_EP_RE  14958592u    // |x_out|^2 partials [4096 blk][64]
#define W_EP_IM  15220736u    // ends 15482880
#define W_XMR    15482880u    // x_mean [16][64]
#define W_XMI    15483904u
#define W_FLR    15484928u    // flux_seq [16][64]
#define W_FLI    15485952u    // ends 15486976
#define W_EIG_RE 16777216u    // BF16 eig: re elems [0,4.19M), im elems [4.19M,8.39M)
// k1 partials AFTER the bf16 eig region (each 65536 floats)
#define W_K1R    20971520u
#define W_K1I    21037056u
#define W_K1E    21102592u
#define W_SMALL  25165824u
#define W_TE     (W_SMALL+0u)
#define W_MTRE   (W_SMALL+3072u)
#define W_MTIM   (W_SMALL+4096u)
#define W_GATE   (W_SMALL+5120u)
#define W_SRCRE  (W_SMALL+6144u)
#define W_SRCIM  (W_SMALL+7168u)
#define W_OPFRE  (W_SMALL+8192u)
#define W_OPFIM  (W_SMALL+9216u)
#define W_OPDRE  (W_SMALL+10240u)
#define W_OPDIM  (W_SMALL+11264u)
#define W_SCALE  (W_SMALL+12288u)

#define XB_IM 4194304u   // bf16-element offset of im half (xcl, xclbase, eig spaces)

typedef __attribute__((ext_vector_type(8))) short bf16x8;
typedef __attribute__((ext_vector_type(4))) float f32x4;

__device__ __forceinline__ unsigned short bfr(float x) {
  __hip_bfloat16 h = __float2bfloat16(x);
  return *(unsigned short*)&h;
}
__device__ __forceinline__ unsigned int pk2(float a, float b) {
  return ((unsigned int)bfr(b) << 16) | (unsigned int)bfr(a);
}
__device__ __forceinline__ float sb2f(short s) {
  return __uint_as_float(((unsigned int)(unsigned short)s) << 16);
}
__device__ __forceinline__ float softplusf(float x) {
  return (x > 20.f) ? x : log1pf(expf(x));
}
__device__ __forceinline__ float gelu_f(float hv) {
  float z = 1.5957691216f * hv + 0.0713548162f * hv * hv * hv;
  return hv * __builtin_amdgcn_rcpf(1.f + __expf(-z));
}

// K2 v2: stage input; wave-local LN stats + k1 partials (shfl); xn bf16; xclbase bf16.
__global__ __launch_bounds__(256) void k2_transpose_ln(
    const float* __restrict__ xre, const float* __restrict__ xim,
    const float* __restrict__ g, const float* __restrict__ bb_, float* ws) {
  int blk = blockIdx.x; int bt = blk >> 6, h = blk & 63;
  __shared__ float tre[64][65], tim[64][65];
  __shared__ float mean_l[64], rstd_l[64];
  int tid = threadIdx.x;
  size_t inbase = (size_t)bt * 262144 + (size_t)h * 64; // + d*4096 + w
  for (int i = tid; i < 1024; i += 256) {
    int d = i >> 4, w4 = (i & 15) * 4;
    float4 vr = *(const float4*)&xre[inbase + (size_t)d * 4096 + w4];
    float4 vi = *(const float4*)&xim[inbase + (size_t)d * 4096 + w4];
    tre[d][w4] = vr.x; tre[d][w4 + 1] = vr.y; tre[d][w4 + 2] = vr.z; tre[d][w4 + 3] = vr.w;
    tim[d][w4] = vi.x; tim[d][w4 + 1] = vi.y; tim[d][w4 + 2] = vi.z; tim[d][w4 + 3] = vi.w;
  }
  __syncthreads();
  // LN stats: (w = tid>>2, part = tid&3) -> 4 adjacent lanes share w -> shfl reduce
  {
    int w = tid >> 2, part = tid & 3;
    float s = 0.f, sq = 0.f;
    for (int dd = part * 16; dd < part * 16 + 16; dd++) {
      float vr = tre[dd][w], vi = tim[dd][w];
      s += vr + vi; sq += vr * vr + vi * vi;
    }
    s += __shfl_xor(s, 1);  s += __shfl_xor(s, 2);
    sq += __shfl_xor(sq, 1); sq += __shfl_xor(sq, 2);
    if (part == 0) {
      float m = s / 128.f, v = sq / 128.f - m * m;
      mean_l[w] = m; rstd_l[w] = rsqrtf(v + 1e-5f);
    }
  }
  // k1 partials: (d = tid>>2, part = tid&3) shfl reduce -> direct global write
  {
    int d = tid >> 2, part = tid & 3;
    float sr = 0.f, si = 0.f, se = 0.f;
    for (int w2 = part * 16; w2 < part * 16 + 16; w2++) {
      float vr = tre[d][w2], vi = tim[d][w2];
      sr += vr; si += vi; se += vr * vr + vi * vi;
    }
    sr += __shfl_xor(sr, 1); sr += __shfl_xor(sr, 2);
    si += __shfl_xor(si, 1); si += __shfl_xor(si, 2);
    se += __shfl_xor(se, 1); se += __shfl_xor(se, 2);
    if (part == 0) {
      int idx = h * 1024 + bt * 64 + d;
      ws[W_K1R + idx] = sr; ws[W_K1I + idx] = si; ws[W_K1E + idx] = se;
    }
  }
  // xclbase bf16 copy (input layout, w-contiguous)
  {
    __hip_bfloat16* xbb = (__hip_bfloat16*)(ws + W_XB);
    for (int i = tid; i < 1024; i += 256) {
      int d = i >> 4, w4 = (i & 15) * 4;
      size_t ob = (size_t)(bt * 64 + d) * 4096 + (size_t)h * 64 + w4;
      *(unsigned int*)&xbb[ob]     = pk2(tre[d][w4],     tre[d][w4 + 1]);
      *(unsigned int*)&xbb[ob + 2] = pk2(tre[d][w4 + 2], tre[d][w4 + 3]);
      *(unsigned int*)&xbb[XB_IM + ob]     = pk2(tim[d][w4],     tim[d][w4 + 1]);
      *(unsigned int*)&xbb[XB_IM + ob + 2] = pk2(tim[d][w4 + 2], tim[d][w4 + 3]);
    }
  }
  __syncthreads(); // mean_l/rstd_l ready
  size_t tokbase = (size_t)blk * 64;
  __hip_bfloat16* xnb = (__hip_bfloat16*)(ws + W_C);
  int c0 = (tid & 63) * 2, wg = tid >> 6;
  float gc0 = g[c0], bc0 = bb_[c0], gc1 = g[c0 + 1], bc1 = bb_[c0 + 1];
  for (int pass = 0; pass < 16; pass++) {
    int w = pass * 4 + wg;
    float m = mean_l[w], rs = rstd_l[w];
    float v0 = (c0 < 64) ? tre[c0][w] : tim[c0 - 64][w];
    float v1 = (c0 + 1 < 64) ? tre[c0 + 1][w] : tim[c0 + 1 - 64][w];
    *(unsigned int*)&xnb[tokbase * 128 + (size_t)w * 128 + c0] =
        pk2((v0 - m) * rs * gc0 + bc0, (v1 - m) * rs * gc1 + bc1);
  }
}

// K1B2B: finalize k1 partials (momentum in LDS) + mom matmul + advection term; 16 x 128
__global__ void k1b2b(const float* __restrict__ mom_w, const float* __restrict__ mom_b,
                      const float* __restrict__ adv_w, const float* __restrict__ dt, float* ws) {
  int bt = blockIdx.x; int t = bt & 7;
  __shared__ float mc[128], outl[128];
  int tid = threadIdx.x; // 128 threads
  if (tid < 64) {
    int d = tid;
    float a = 0.f, b = 0.f, c = 0.f;
    for (int h = 0; h < 64; h++) {
      int idx = h * 1024 + bt * 64 + d;
      a += ws[W_K1R + idx]; b += ws[W_K1I + idx]; c += ws[W_K1E + idx];
    }
    ws[W_TE + bt * 64 + d] = c / 4096.f;
    mc[d] = a / 4096.f;
    mc[64 + d] = b / 4096.f;
  }
  __syncthreads();
  float acc = mom_b[tid];
  for (int k = 0; k < 128; k++) acc += mc[k] * mom_w[k * 128 + tid];
  outl[tid] = acc;
  __syncthreads();
  if (tid < 64) {
    float f = adv_w[0] * dt[t];
    ws[W_MTRE + bt * 64 + tid] = outl[tid] * f;
    ws[W_MTIM + bt * 64 + tid] = outl[64 + tid] * f;
  }
}

// K0w: bf16 weight prep
__global__ void k0_wprep(const float* __restrict__ w1, const float* __restrict__ w2,
                         const float* __restrict__ cw,
                         const float* __restrict__ enc_re, const float* __restrict__ enc_im,
                         const float* __restrict__ dec_re, const float* __restrict__ dec_im,
                         float* ws) {
  __hip_bfloat16* w1f = (__hip_bfloat16*)(ws + W_W1T);
  __hip_bfloat16* w2f = (__hip_bfloat16*)(ws + W_W2T);
  __hip_bfloat16* cwt = (__hip_bfloat16*)(ws + W_CWT);
  __hip_bfloat16* encM = (__hip_bfloat16*)(ws + W_ENCM);
  __hip_bfloat16* decM = (__hip_bfloat16*)(ws + W_DECM);
  int idx = blockIdx.x * 256 + threadIdx.x; // 0..147455
  if (idx < 131072) {
    {
      int j = idx & 7, lane = (idx >> 3) & 63, kt = (idx >> 9) & 3, nt = (idx >> 11) & 15, e = idx >> 15;
      int cout = nt * 16 + (lane & 15);
      int cin = kt * 32 + (lane >> 4) * 8 + j;
      w1f[idx] = __float2bfloat16(w1[((size_t)(e * 128 + cin)) * 256 + cout]);
    }
    {
      int j = idx & 7, lane = (idx >> 3) & 63, kt = (idx >> 9) & 7, nt = (idx >> 12) & 7, e = idx >> 15;
      int cout = nt * 16 + (lane & 15);
      int cin = kt * 32 + (lane >> 4) * 8 + j;
      w2f[idx] = __float2bfloat16(w2[((size_t)(e * 256 + cin)) * 128 + cout]);
    }
  }
  if (idx < 147456) {
    int j = idx & 7, lane = (idx >> 3) & 63, kt = (idx >> 9) & 3, r = idx >> 11;
    int nt = r & 7, tap = r >> 3;
    int cout = nt * 16 + (lane & 15);
    int cin = kt * 32 + (lane >> 4) * 8 + j;
    cwt[idx] = __float2bfloat16(cw[((size_t)(tap * 128 + cin)) * 128 + cout]);
  }
  if (idx < 16384) {
    int jj = idx & 7, lane = (idx >> 3) & 63, kt = (idx >> 9) & 3, nt = idx >> 11;
    int jc = nt * 16 + (lane & 15);
    int k = kt * 32 + (lane >> 4) * 8 + jj;
    float ve, vd;
    if (k < 64) {
      ve = (jc < 64) ? enc_re[k * 64 + jc] : enc_im[k * 64 + (jc - 64)];
      vd = (jc < 64) ? dec_re[k * 64 + jc] : dec_im[k * 64 + (jc - 64)];
    } else {
      int kk = k - 64;
      ve = (jc < 64) ? -enc_im[kk * 64 + jc] : enc_re[kk * 64 + (jc - 64)];
      vd = (jc < 64) ? -dec_im[kk * 64 + jc] : dec_re[kk * 64 + (jc - 64)];
    }
    encM[idx] = __float2bfloat16(ve);
    decM[idx] = __float2bfloat16(vd);
  }
}

// K3: 3x3 conv (bf16 MFMA); xcl(bf16) = xclbase(bf16) + conv + cb + mom; FUSED enc GEMM.
__global__ __launch_bounds__(256) void k3_conv_enc(const float* __restrict__ cb, float* ws) {
  int blk = blockIdx.x; int bt = blk >> 6, h = blk & 63;
  const __hip_bfloat16* xnb = (const __hip_bfloat16*)(ws + W_C);
  const __hip_bfloat16* cwt = (const __hip_bfloat16*)(ws + W_CWT);
  const __hip_bfloat16* encM = (const __hip_bfloat16*)(ws + W_ENCM);
  const __hip_bfloat16* xbb = (const __hip_bfloat16*)(ws + W_XB);
  __hip_bfloat16* xclb = (__hip_bfloat16*)ws;
  __hip_bfloat16* eigb = (__hip_bfloat16*)(ws + W_EIG_RE);
  __shared__ __align__(16) char smem[3 * 66 * 136 * 2]; // xin; reused as A-tile after conv
  __hip_bfloat16 (*xin)[66][136] = (__hip_bfloat16(*)[66][136])smem;
  char* A = smem; // bf16 [64 rows][256B], XOR-swizzled
  int tid = threadIdx.x, lane = tid & 63, wv = tid >> 6;
  int arow = lane & 15, kgrp = (lane >> 4) * 8, rbase = (lane >> 4) * 4;

  for (int r = 0; r < 3; r++) {
    int hh = h + r - 1;
    if (hh < 0 || hh >= 64) {
      unsigned int* z = (unsigned int*)&xin[r][0][0];
      for (int i = tid; i < 4488; i += 256) z[i] = 0u;
    } else {
      if (tid < 68) *(unsigned int*)&xin[r][0][tid * 2] = 0u;
      else if (tid < 136) *(unsigned int*)&xin[r][65][(tid - 136 + 68) * 2] = 0u;
      const __hip_bfloat16* src = xnb + ((size_t)bt * 4096 + (size_t)hh * 64) * 128;
      for (int i = tid; i < 1024; i += 256) {
        int wp = (i >> 4) + 1, c8 = (i & 15) * 8;
        *(bf16x8*)&xin[r][wp][c8] = *(const bf16x8*)&src[(size_t)(wp - 1) * 128 + c8];
      }
    }
  }
  __syncthreads();

  f32x4 oacc[4][2];
  #pragma unroll
  for (int m = 0; m < 4; m++) {
    oacc[m][0] = (f32x4){0.f, 0.f, 0.f, 0.f};
    oacc[m][1] = (f32x4){0.f, 0.f, 0.f, 0.f};
  }

  for (int tap = 0; tap < 9; tap++) {
    int kh = tap / 3, kw = tap % 3;
    const __hip_bfloat16* wt0 = cwt + ((size_t)(tap * 8 + wv * 2) * 4) * 512 + lane * 8;
    #pragma unroll
    for (int kt = 0; kt < 4; kt++) {
      bf16x8 a[4];
      #pragma unroll
      for (int m = 0; m < 4; m++)
        a[m] = *(const bf16x8*)&xin[kh][m * 16 + arow + kw][kt * 32 + kgrp];
      bf16x8 b0 = *(const bf16x8*)&wt0[(size_t)kt * 512];
      bf16x8 b1 = *(const bf16x8*)&wt0[(size_t)(kt + 4) * 512];
      #pragma unroll
      for (int m = 0; m < 4; m++) {
        oacc[m][0] = __builtin_amdgcn_mfma_f32_16x16x32_bf16(a[m], b0, oacc[m][0], 0, 0, 0);
        oacc[m][1] = __builtin_amdgcn_mfma_f32_16x16x32_bf16(a[m], b1, oacc[m][1], 0, 0, 0);
      }
    }
  }
  __syncthreads(); // xin dead -> A-tile may overwrite

  size_t rowtok = (size_t)blk * 64;
  #pragma unroll
  for (int n = 0; n < 2; n++) {
    int cout = (wv * 2 + n) * 16 + arow;
    bool isre = cout < 64;
    int d = cout & 63;
    float add = cb[cout] + ws[(isre ? W_MTRE : W_MTIM) + bt * 64 + d];
    size_t xb = isre ? 0u : XB_IM;
    const __hip_bfloat16* xsrc = xbb + xb + (size_t)(bt * 64 + d) * 4096 + (size_t)h * 64;
    #pragma unroll
    for (int m = 0; m < 4; m++) {
      unsigned int u0 = *(const unsigned int*)&xsrc[m * 16 + rbase];
      unsigned int u1 = *(const unsigned int*)&xsrc[m * 16 + rbase + 2];
      float xo0 = __uint_as_float(u0 << 16);
      float xo1 = __uint_as_float(u0 & 0xffff0000u);
      float xo2 = __uint_as_float(u1 << 16);
      float xo3 = __uint_as_float(u1 & 0xffff0000u);
      #pragma unroll
      for (int r = 0; r < 4; r++) {
        int w = m * 16 + rbase + r;
        float xo = (r == 0) ? xo0 : (r == 1) ? xo1 : (r == 2) ? xo2 : xo3;
        float v = xo + oacc[m][n][r] + add;
        xclb[xb + (rowtok + w) * 64 + d] = __float2bfloat16(v);
        *(__hip_bfloat16*)(A + w * 256 + ((cout * 2) ^ ((w & 7) << 4))) = __float2bfloat16(v);
      }
    }
  }
  __syncthreads();

  // fused enc GEMM 64x128x128 -> eig (bf16), + x_mean partials (f32)
  f32x4 acc[4][2];
  #pragma unroll
  for (int m = 0; m < 4; m++) {
    acc[m][0] = (f32x4){0.f, 0.f, 0.f, 0.f};
    acc[m][1] = (f32x4){0.f, 0.f, 0.f, 0.f};
  }
  #pragma unroll
  for (int kt = 0; kt < 4; kt++) {
    bf16x8 a[4];
    #pragma unroll
    for (int m = 0; m < 4; m++)
      a[m] = *(const bf16x8*)(A + (m * 16 + arow) * 256 + (((kt * 32 + kgrp) * 2) ^ ((arow & 7) << 4)));
    bf16x8 b0 = *(const bf16x8*)&encM[(((size_t)(wv * 2 + 0) * 4 + kt) * 64 + lane) * 8];
    bf16x8 b1 = *(const bf16x8*)&encM[(((size_t)(wv * 2 + 1) * 4 + kt) * 64 + lane) * 8];
    #pragma unroll
    for (int m = 0; m < 4; m++) {
      acc[m][0] = __builtin_amdgcn_mfma_f32_16x16x32_bf16(a[m], b0, acc[m][0], 0, 0, 0);
      acc[m][1] = __builtin_amdgcn_mfma_f32_16x16x32_bf16(a[m], b1, acc[m][1], 0, 0, 0);
    }
  }
  #pragma unroll
  for (int n = 0; n < 2; n++) {
    int jc = (wv * 2 + n) * 16 + arow;
    size_t eb = (jc < 64) ? 0u : XB_IM;
    int col = jc & 63;
    #pragma unroll
    for (int m = 0; m < 4; m++)
      #pragma unroll
      for (int r = 0; r < 4; r++)
        eigb[eb + (rowtok + m * 16 + rbase + r) * 64 + col] = __float2bfloat16(acc[m][n][r]);
    float s = 0.f;
    #pragma unroll
    for (int m = 0; m < 4; m++)
      #pragma unroll
      for (int r = 0; r < 4; r++) s += acc[m][n][r];
    s += __shfl_xor(s, 16);
    s += __shfl_xor(s, 32);
    if (lane < 16)
      ws[(jc < 64 ? W_XMP_RE : W_XMP_IM) + (size_t)blk * 64 + col] = s;
  }
}

// K6a: x_mean finalize; 16 blocks x 64 threads
__global__ void k6a_xm(float* ws) {
  int bt = blockIdx.x, j = threadIdx.x;
  float sr = 0.f, si = 0.f;
  for (int q = 0; q < 64; q++) {
    sr += ws[W_XMP_RE + (size_t)(bt * 64 + q) * 64 + j];
    si += ws[W_XMP_IM + (size_t)(bt * 64 + q) * 64 + j];
  }
  ws[W_XMR + bt * 64 + j] = sr / 4096.f;
  ws[W_XMI + bt * 64 + j] = si / 4096.f;
}

// K6b: X_flux matmul + T=8 flux scan (the only serial part); 1 block x 256
__global__ void k6b_flux(const float* __restrict__ fin_re, const float* __restrict__ fin_im,
                         const float* __restrict__ flux_a_re, const float* __restrict__ flux_a_im,
                         float* ws) {
  __shared__ float Xfr[1024], Xfi[1024];
  int tid = threadIdx.x;
  for (int i = tid; i < 1024; i += 256) {
    int bt = i >> 6, j = i & 63;
    float ar = 0.f, ai = 0.f;
    for (int d = 0; d < 64; d++) {
      float xr = ws[W_XMR + bt * 64 + d], xi = ws[W_XMI + bt * 64 + d];
      float wr = fin_re[d * 64 + j], wi = fin_im[d * 64 + j];
      ar += xr * wr - xi * wi; ai += xr * wi + xi * wr;
    }
    Xfr[i] = ar; Xfi[i] = ai;
  }
  __syncthreads();
  if (tid < 128) {
    int b = tid >> 6, j = tid & 63;
    float mag = expf(-softplusf(flux_a_re[j]));
    float aar = mag * cosf(flux_a_im[j]), aai = mag * sinf(flux_a_im[j]);
    float sr = 0.f, si = 0.f;
    for (int t = 0; t < 8; t++) {
      int idx = (b * 8 + t) * 64 + j;
      float nr = aar * sr - aai * si + Xfr[idx];
      float ni = aar * si + aai * sr + Xfi[idx];
      sr = nr; si = ni;
      ws[W_FLR + idx] = sr; ws[W_FLI + idx] = si;
    }
  }
}

// K6c: source/gate/op_decay; 16 blocks (bt) x 256 threads
__global__ void k6c_gate(const float* __restrict__ fproj_re, const float* __restrict__ fproj_im,
                         const float* __restrict__ gate_w, const float* __restrict__ gate_b,
                         const float* __restrict__ lam_re, const float* __restrict__ lam_im,
                         const float* __restrict__ dt, float* ws) {
  int bt = blockIdx.x;
  __shared__ float flr[64], fli[64];
  int tid = threadIdx.x;
  if (tid < 64) { flr[tid] = ws[W_FLR + bt * 64 + tid]; fli[tid] = ws[W_FLI + bt * 64 + tid]; }
  __syncthreads();
  int j = tid >> 2, part = tid & 3;
  float ar = 0.f, ai = 0.f, lg = 0.f;
  for (int d = part * 16; d < part * 16 + 16; d++) {
    float fr = flr[d], fi = fli[d];
    float wr = fproj_re[d * 64 + j], wi = fproj_im[d * 64 + j];
    ar += fr * wr - fi * wi; ai += fr * wi + fi * wr;
    lg += fr * gate_w[d * 64 + j] + fi * gate_w[(64 + d) * 64 + j];
  }
  ar += __shfl_xor(ar, 1); ar += __shfl_xor(ar, 2);
  ai += __shfl_xor(ai, 1); ai += __shfl_xor(ai, 2);
  lg += __shfl_xor(lg, 1); lg += __shfl_xor(lg, 2);
  if (part == 0) {
    int idx = bt * 64 + j;
    ws[W_SRCRE + idx] = ar; ws[W_SRCIM + idx] = ai;
    ws[W_GATE + idx] = 1.f / (1.f + expf(-(lg + gate_b[j])));
  }
  if (tid < 64) {
    int d = tid, t = bt & 7;
    float lr = -softplusf(lam_re[d]), li = lam_im[d];
    float dtv = dt[t];
    float mag = expf(lr * dtv);
    float dr = mag * cosf(li * dtv), di = mag * sinf(li * dtv);
    int idx = bt * 64 + d;
    ws[W_OPDRE + idx] = dr; ws[W_OPDIM + idx] = di;
    float omr = dr - 1.f, omi = di;
    float den = lr * lr + li * li;
    ws[W_OPFRE + idx] = (omr * lr + omi * li) / den;
    ws[W_OPFIM + idx] = (omi * lr - omr * li) / den;
  }
}

// K7_DEC: fused time-scan + dec cgemm + |x_out|^2 partials; u32-paired loads, dbuf A-tile.
__global__ __launch_bounds__(256) void k7_dec(const float* __restrict__ nre,
                                              const float* __restrict__ nim,
                                              const float* __restrict__ dt, float* ws) {
  int blk = blockIdx.x;
  int b = blk >> 8, h = (blk >> 2) & 63, wq = blk & 3;
  const __hip_bfloat16* decM = (const __hip_bfloat16*)(ws + W_DECM);
  __hip_bfloat16* eigb = (__hip_bfloat16*)(ws + W_EIG_RE);
  __shared__ float gl[8][64], srl[8][64], sil[8][64], ofr[8][64], ofi[8][64], odr[8][64], odi[8][64];
  __shared__ __align__(16) char A[2][4096];
  __shared__ float dts[8];
  int tid = threadIdx.x, lane = tid & 63, wv = tid >> 6;
  int arow = lane & 15, kgrp = (lane >> 4) * 8, rbase = (lane >> 4) * 4;
  for (int i = tid; i < 512; i += 256) {
    int t = i >> 6, d = i & 63, idx = (b * 8 + t) * 64 + d;
    gl[t][d]  = ws[W_GATE + idx];
    srl[t][d] = ws[W_SRCRE + idx]; sil[t][d] = ws[W_SRCIM + idx];
    ofr[t][d] = ws[W_OPFRE + idx]; ofi[t][d] = ws[W_OPFIM + idx];
    odr[t][d] = ws[W_OPDRE + idx]; odi[t][d] = ws[W_OPDIM + idx];
  }
  if (tid < 8) dts[tid] = dt[tid];
  __syncthreads();

  int dp = (tid & 31) * 2, wslot = tid >> 5;
  float ur[2][2], ui[2][2];
  #pragma unroll
  for (int a_ = 0; a_ < 2; a_++) { ur[a_][0] = 0.f; ur[a_][1] = 0.f; ui[a_][0] = 0.f; ui[a_][1] = 0.f; }

  for (int t = 0; t < 8; t++) {
    float ns = 0.01f * sqrtf(dts[t]);
    size_t tokb = ((size_t)(b * 8 + t) * 64 + h) * 64 + (size_t)wq * 16;
    char* At = A[t & 1];
    float g0 = gl[t][dp],  g1 = gl[t][dp + 1];
    float s0 = srl[t][dp], s1 = srl[t][dp + 1];
    float q0 = sil[t][dp], q1 = sil[t][dp + 1];
    float f0 = ofr[t][dp], f1 = ofr[t][dp + 1];
    float e0 = ofi[t][dp], e1 = ofi[t][dp + 1];
    float r0 = odr[t][dp], r1 = odr[t][dp + 1];
    float o0 = odi[t][dp], o1 = odi[t][dp + 1];
    #pragma unroll
    for (int wi = 0; wi < 2; wi++) {
      int wl = wslot + wi * 8;
      size_t off = (tokb + wl) * 64 + dp;
      unsigned int re2 = *(const unsigned int*)&eigb[off];
      unsigned int im2 = *(const unsigned int*)&eigb[XB_IM + off];
      float2 nr2 = *(const float2*)&nre[off];
      float2 ni2 = *(const float2*)&nim[off];
      float uo0, vo0, uo1, vo1;
      {
        float er_ = __uint_as_float(re2 << 16);
        float ei_ = __uint_as_float(im2 << 16);
        float fre = er_ * g0 + s0 * (1.f - g0);
        float fim = ei_ * g0 + q0 * (1.f - g0);
        float utr = fre * f0 - fim * e0;
        float uti = fre * e0 + fim * f0;
        float nur = r0 * ur[wi][0] - o0 * ui[wi][0] + utr;
        float nui = r0 * ui[wi][0] + o0 * ur[wi][0] + uti;
        ur[wi][0] = nur; ui[wi][0] = nui;
        uo0 = nur + ns * nr2.x; vo0 = nui + ns * ni2.x;
      }
      {
        float er_ = __uint_as_float(re2 & 0xffff0000u);
        float ei_ = __uint_as_float(im2 & 0xffff0000u);
        float fre = er_ * g1 + s1 * (1.f - g1);
        float fim = ei_ * g1 + q1 * (1.f - g1);
        float utr = fre * f1 - fim * e1;
        float uti = fre * e1 + fim * f1;
        float nur = r1 * ur[wi][1] - o1 * ui[wi][1] + utr;
        float nui = r1 * ui[wi][1] + o1 * ur[wi][1] + uti;
        ur[wi][1] = nur; ui[wi][1] = nui;
        uo1 = nur + ns * nr2.y; vo1 = nui + ns * ni2.y;
      }
      int sw = (wl & 7) << 4;
      *(unsigned int*)(At + wl * 256 + ((dp * 2) ^ sw)) = pk2(uo0, uo1);
      *(unsigned int*)(At + wl * 256 + ((128 + dp * 2) ^ sw)) = pk2(vo0, vo1);
    }
    __syncthreads();
    f32x4 acc[2];
    acc[0] = (f32x4){0.f, 0.f, 0.f, 0.f};
    acc[1] = (f32x4){0.f, 0.f, 0.f, 0.f};
    #pragma unroll
    for (int kt = 0; kt < 4; kt++) {
      bf16x8 a0 = *(const bf16x8*)(At + arow * 256 + (((kt * 32 + kgrp) * 2) ^ ((arow & 7) << 4)));
      bf16x8 b0 = *(const bf16x8*)&decM[(((size_t)(wv * 2 + 0) * 4 + kt) * 64 + lane) * 8];
      bf16x8 b1 = *(const bf16x8*)&decM[(((size_t)(wv * 2 + 1) * 4 + kt) * 64 + lane) * 8];
      acc[0] = __builtin_amdgcn_mfma_f32_16x16x32_bf16(a0, b0, acc[0], 0, 0, 0);
      acc[1] = __builtin_amdgcn_mfma_f32_16x16x32_bf16(a0, b1, acc[1], 0, 0, 0);
    }
    #pragma unroll
    for (int n = 0; n < 2; n++) {
      int jc = (wv * 2 + n) * 16 + arow;
      size_t eb = (jc < 64) ? 0u : XB_IM;
      int col = jc & 63;
      #pragma unroll
      for (int r = 0; r < 4; r++)
        eigb[eb + (tokb + rbase + r) * 64 + col] = __float2bfloat16(acc[n][r]);
      float s = acc[n][0] * acc[n][0] + acc[n][1] * acc[n][1]
              + acc[n][2] * acc[n][2] + acc[n][3] * acc[n][3];
      s += __shfl_xor(s, 16);
      s += __shfl_xor(s, 32);
      if (lane < 16)
        ws[(jc < 64 ? W_EP_RE : W_EP_IM)
           + (size_t)((b * 8 + t) * 256 + h * 4 + wq) * 64 + col] = s;
    }
  }
}

// K9b: combine |x_out|^2 partials -> energy rescale factor per (bt,d)
__global__ void k9b_scale(const float* __restrict__ escale, float* ws) {
  int bt = blockIdx.x; int j = threadIdx.x; // 16 x 64
  float s = 0.f;
  for (int q = 0; q < 256; q++) {
    size_t idx = (size_t)(bt * 256 + q) * 64 + j;
    s += ws[W_EP_RE + idx] + ws[W_EP_IM + idx];
  }
  float cur = s / 4096.f;
  float te = ws[W_TE + bt * 64 + j];
  float ratio = te / (cur + 1e-8f);
  ratio = fminf(fmaxf(ratio, 0.5f), 2.0f);
  ws[W_SCALE + bt * 64 + j] = 1.f + escale[0] * (sqrtf(ratio) - 1.f);
}

// K11 v12: v11 (swapped layer1, shfl front-end, direct epilogue) with SINGLE hbuf
// -> 50KB LDS -> 3 blocks/CU (6 waves/SIMD). 2 barriers/expert, 8 total.
__global__ __launch_bounds__(512) void k11_moe(
    const float* __restrict__ rw, const float* __restrict__ rb,
    const float* __restrict__ b1, const float* __restrict__ b2,
    const float* __restrict__ g2, const float* __restrict__ b2_,
    float* __restrict__ ws, float* __restrict__ out) {
  int blk = blockIdx.x; int bt = blk >> 6, h = blk & 63;
  const __hip_bfloat16* w1f = (const __hip_bfloat16*)(ws + W_W1T);
  const __hip_bfloat16* w2f = (const __hip_bfloat16*)(ws + W_W2T);
  const __hip_bfloat16* xclb = (const __hip_bfloat16*)ws;
  const __hip_bfloat16* eigb = (const __hip_bfloat16*)(ws + W_EIG_RE);
  // smem: lt [0,16384) | hbuf [16384,49152)  -> 48 KiB (+pl) => 3 blocks/CU
  __shared__ __align__(16) char smem[49152];
  __shared__ float pl[64][4];
  char* lt = smem;
  char* hb = smem + 16384;
  int tid = threadIdx.x, lane = tid & 63, wv = tid >> 6; // wv in [0,8)
  int arow = lane & 15, kgrp = (lane >> 4) * 8, rbase = (lane >> 4) * 4;
  size_t tokbase = (size_t)blk * 64;

  // ---- phase 1 (barrier-free): LN + router via wave shuffles ----
  int w = tid >> 3, part = tid & 7;
  int c0 = part * 16, dbase = (part & 3) * 16;
  const __hip_bfloat16* rp = eigb + ((part < 4) ? 0u : XB_IM) + (tokbase + w) * 64 + dbase;
  const float* scg = ws + W_SCALE + bt * 64 + dbase;
  float an[16];
  {
    bf16x8 h0 = *(const bf16x8*)rp;
    bf16x8 h1 = *(const bf16x8*)(rp + 8);
    float f[16];
    #pragma unroll
    for (int j = 0; j < 8; j++) {
      f[j]     = sb2f(h0[j]) * scg[j];
      f[8 + j] = sb2f(h1[j]) * scg[8 + j];
    }
    float s = 0.f, sq = 0.f;
    #pragma unroll
    for (int k = 0; k < 16; k++) { s += f[k]; sq += f[k] * f[k]; }
    s  += __shfl_xor(s, 1);  s  += __shfl_xor(s, 2);  s  += __shfl_xor(s, 4);
    sq += __shfl_xor(sq, 1); sq += __shfl_xor(sq, 2); sq += __shfl_xor(sq, 4);
    float m = s / 128.f, v = sq / 128.f - m * m;
    float rstd = rsqrtf(v + 1e-5f);
    int szw = (w & 7) << 4;
    #pragma unroll
    for (int q = 0; q < 4; q++) {
      int c = c0 + q * 4;
      float a0 = (f[q * 4 + 0] - m) * rstd * g2[c]     + b2_[c];
      float a1 = (f[q * 4 + 1] - m) * rstd * g2[c + 1] + b2_[c + 1];
      float a2 = (f[q * 4 + 2] - m) * rstd * g2[c + 2] + b2_[c + 2];
      float a3 = (f[q * 4 + 3] - m) * rstd * g2[c + 3] + b2_[c + 3];
      an[q * 4 + 0] = a0; an[q * 4 + 1] = a1; an[q * 4 + 2] = a2; an[q * 4 + 3] = a3;
      *(unsigned int*)(lt + w * 256 + ((c * 2) ^ szw)) = pk2(a0, a1);
      *(unsigned int*)(lt + w * 256 + (((c + 2) * 2) ^ szw)) = pk2(a2, a3);
    }
    float l0 = 0.f, l1 = 0.f, l2 = 0.f, l3 = 0.f;
    #pragma unroll
    for (int k = 0; k < 16; k++) {
      float4 r4 = *(const float4*)&rw[(c0 + k) * 4];
      l0 += an[k] * r4.x; l1 += an[k] * r4.y; l2 += an[k] * r4.z; l3 += an[k] * r4.w;
    }
    l0 += __shfl_xor(l0, 1); l0 += __shfl_xor(l0, 2); l0 += __shfl_xor(l0, 4);
    l1 += __shfl_xor(l1, 1); l1 += __shfl_xor(l1, 2); l1 += __shfl_xor(l1, 4);
    l2 += __shfl_xor(l2, 1); l2 += __shfl_xor(l2, 2); l2 += __shfl_xor(l2, 4);
    l3 += __shfl_xor(l3, 1); l3 += __shfl_xor(l3, 2); l3 += __shfl_xor(l3, 4);
    l0 += rb[0]; l1 += rb[1]; l2 += rb[2]; l3 += rb[3];
    float mx = fmaxf(fmaxf(l0, l1), fmaxf(l2, l3));
    float e0 = expf(l0 - mx), e1 = expf(l1 - mx), e2 = expf(l2 - mx), e3 = expf(l3 - mx);
    float rs = __builtin_amdgcn_rcpf(e0 + e1 + e2 + e3);
    if (part == 0) {
      float4 p; p.x = e0 * rs; p.y = e1 * rs; p.z = e2 * rs; p.w = e3 * rs;
      *(float4*)&pl[w][0] = p;
    }
  }
  __syncthreads(); // ltok + pl ready

  // out accumulator init = tok residual; wave owns out cols [wv*16, wv*16+16)
  f32x4 oacc[4];
  #pragma unroll
  for (int m = 0; m < 4; m++) {
    int col = wv * 16 + arow;
    oacc[m] = (f32x4){0.f, 0.f, 0.f, 0.f};
    #pragma unroll
    for (int r = 0; r < 4; r++) {
      int row = m * 16 + rbase + r;
      oacc[m][r] = __bfloat162float(
          *(const __hip_bfloat16*)(lt + row * 256 + ((col * 2) ^ ((row & 7) << 4))));
    }
  }

  // ---- expert loop: single hbuf, layer1 -> barrier -> layer2 -> barrier ----
  for (int e = 0; e < 4; e++) {
    if (e) __syncthreads(); // prev layer2 reads done before overwrite
    // layer1 SWAPPED: mfma(w1_frag, lt_frag) -> reg axis = hid, lane axis = token
    f32x4 acc1[4][2]; // [m token-tile][n hid-tile]
    #pragma unroll
    for (int m = 0; m < 4; m++) {
      acc1[m][0] = (f32x4){0.f, 0.f, 0.f, 0.f};
      acc1[m][1] = (f32x4){0.f, 0.f, 0.f, 0.f};
    }
    #pragma unroll
    for (int kt = 0; kt < 4; kt++) {
      bf16x8 a[4];
      #pragma unroll
      for (int m = 0; m < 4; m++) {
        int row = m * 16 + arow;
        a[m] = *(const bf16x8*)(lt + row * 256 + (((kt * 32 + kgrp) * 2) ^ ((arow & 7) << 4)));
      }
      bf16x8 b0 = *(const bf16x8*)&w1f[(((size_t)(e * 16 + wv * 2 + 0) * 4 + kt) * 64 + lane) * 8];
      bf16x8 b1 = *(const bf16x8*)&w1f[(((size_t)(e * 16 + wv * 2 + 1) * 4 + kt) * 64 + lane) * 8];
      #pragma unroll
      for (int m = 0; m < 4; m++) {
        acc1[m][0] = __builtin_amdgcn_mfma_f32_16x16x32_bf16(b0, a[m], acc1[m][0], 0, 0, 0);
        acc1[m][1] = __builtin_amdgcn_mfma_f32_16x16x32_bf16(b1, a[m], acc1[m][1], 0, 0, 0);
      }
    }
    // bias + gelu -> hb [token row][512B hid]: 4 consecutive hid per lane -> one 8B write
    #pragma unroll
    for (int n = 0; n < 2; n++) {
      int hid0 = (wv * 2 + n) * 16 + rbase;
      float4 bv4 = *(const float4*)&b1[e * 256 + hid0];
      #pragma unroll
      for (int m = 0; m < 4; m++) {
        int token = m * 16 + arow;
        unsigned int lo = pk2(gelu_f(acc1[m][n][0] + bv4.x), gelu_f(acc1[m][n][1] + bv4.y));
        unsigned int hi = pk2(gelu_f(acc1[m][n][2] + bv4.z), gelu_f(acc1[m][n][3] + bv4.w));
        int bo = (hid0 * 2) ^ ((token & 7) << 4);
        *(unsigned long long*)(hb + token * 512 + bo) =
            ((unsigned long long)hi << 32) | (unsigned long long)lo;
      }
    }
    __syncthreads(); // hbuf ready
    // layer2: wave owns out n-tile wv
    f32x4 acc2[4];
    #pragma unroll
    for (int m = 0; m < 4; m++) acc2[m] = (f32x4){0.f, 0.f, 0.f, 0.f};
    #pragma unroll
    for (int kt = 0; kt < 8; kt++) {
      bf16x8 a2[4];
      #pragma unroll
      for (int m = 0; m < 4; m++) {
        int row = m * 16 + arow;
        a2[m] = *(const bf16x8*)(hb + row * 512 + (((kt * 32 + kgrp) * 2) ^ ((arow & 7) << 4)));
      }
      bf16x8 bb = *(const bf16x8*)&w2f[(((size_t)(e * 8 + wv) * 8 + kt) * 64 + lane) * 8];
      #pragma unroll
      for (int m = 0; m < 4; m++)
        acc2[m] = __builtin_amdgcn_mfma_f32_16x16x32_bf16(a2[m], bb, acc2[m], 0, 0, 0);
    }
    {
      int col = wv * 16 + arow;
      float bv2 = b2[e * 128 + col];
      #pragma unroll
      for (int m = 0; m < 4; m++)
        #pragma unroll
        for (int r = 0; r < 4; r++)
          oacc[m][r] += pl[m * 16 + rbase + r][e] * (acc2[m][r] + bv2);
    }
  }

  // direct epilogue: residual (bf16 xcl, L2) + float4 stores straight to out
  {
    int col = wv * 16 + arow;
    size_t xb = (col < 64) ? 0u : XB_IM;
    int dd = col & 63;
    size_t obase = (size_t)(col >> 6) * 4194304 + (size_t)bt * 262144
                 + (size_t)dd * 4096 + (size_t)h * 64;
    #pragma unroll
    for (int m = 0; m < 4; m++) {
      int wtb = m * 16 + rbase;
      float4 v;
      #pragma unroll
      for (int r = 0; r < 4; r++) {
        float res = __bfloat162float(xclb[xb + (tokbase + wtb + r) * 64 + dd]);
        ((float*)&v)[r] = oacc[m][r] + res;
      }
      *(float4*)&out[obase + wtb] = v;
    }
  }
}

extern "C" void kernel_launch(void* const* d_in, const int* in_sizes, int n_in,
                              void* d_out, int out_size, void* d_ws, size_t ws_size,
                              hipStream_t stream) {
  const float* x_re      = (const float*)d_in[0];
  const float* x_im      = (const float*)d_in[1];
  const float* dt        = (const float*)d_in[2];
  const float* ln_s_g    = (const float*)d_in[3];
  const float* ln_s_b    = (const float*)d_in[4];
  const float* conv_w    = (const float*)d_in[5];
  const float* conv_b    = (const float*)d_in[6];
  const float* mom_w     = (const float*)d_in[7];
  const float* mom_b     = (const float*)d_in[8];
  const float* adv_w     = (const float*)d_in[9];
  const float* enc_re    = (const float*)d_in[10];
  const float* enc_im    = (const float*)d_in[11];
  const float* dec_re    = (const float*)d_in[12];
  const float* dec_im    = (const float*)d_in[13];
  const float* flux_a_re = (const float*)d_in[14];
  const float* flux_a_im = (const float*)d_in[15];
  const float* fin_re    = (const float*)d_in[16];
  const float* fin_im    = (const float*)d_in[17];
  const float* fproj_re  = (const float*)d_in[18];
  const float* fproj_im  = (const float*)d_in[19];
  const float* gate_w    = (const float*)d_in[20];
  const float* gate_b    = (const float*)d_in[21];
  const float* lam_re    = (const float*)d_in[22];
  const float* lam_im    = (const float*)d_in[23];
  const float* noise_re  = (const float*)d_in[24];
  const float* noise_im  = (const float*)d_in[25];
  const float* e_scale   = (const float*)d_in[26];
  const float* ln_t_g    = (const float*)d_in[27];
  const float* ln_t_b    = (const float*)d_in[28];
  const float* router_w  = (const float*)d_in[29];
  const float* router_b  = (const float*)d_in[30];
  const float* w1        = (const float*)d_in[31];
  const float* b1        = (const float*)d_in[32];
  const float* w2        = (const float*)d_in[33];
  const float* b2        = (const float*)d_in[34];
  float* ws  = (float*)d_ws;
  float* out = (float*)d_out;

  k0_wprep<<<576, 256, 0, stream>>>(w1, w2, conv_w, enc_re, enc_im, dec_re, dec_im, ws);
  k2_transpose_ln<<<1024, 256, 0, stream>>>(x_re, x_im, ln_s_g, ln_s_b, ws);
  k1b2b<<<16, 128, 0, stream>>>(mom_w, mom_b, adv_w, dt, ws);
  k3_conv_enc<<<1024, 256, 0, stream>>>(conv_b, ws);
  k6a_xm<<<16, 64, 0, stream>>>(ws);
  k6b_flux<<<1, 256, 0, stream>>>(fin_re, fin_im, flux_a_re, flux_a_im, ws);
  k6c_gate<<<16, 256, 0, stream>>>(fproj_re, fproj_im, gate_w, gate_b, lam_re, lam_im, dt, ws);
  k7_dec<<<512, 256, 0, stream>>>(noise_re, noise_im, dt, ws);
  k9b_scale<<<16, 64, 0, stream>>>(e_scale, ws);
  k11_moe<<<1024, 512, 0, stream>>>(router_w, router_b, b1, b2, ln_t_g, ln_t_b, ws, out);
}

// Round 24
// 225.781 us; speedup vs baseline: 1.0336x; 1.0336x over previous
//
#include <hip/hip_runtime.h>
#include <hip/hip_bf16.h>
#include <math.h>

// Problem constants: B=2,T=8,D=64,H=64,W=64,D2=128,E=4,HID=256
// token index = ((bt)*64 + h)*64 + w ; bt = b*8+t ; NTOK = 65536

// -------- workspace layout (float offsets) --------
// xcl BF16 at ws+0: re elems [0,4.19M), im [4.19M,8.39M) -> floats [0, 4194304)
#define W_XB     4194304u     // xclbase BF16 (input, [bt][d][h][w] layout): floats [4.19M, 8.39M)
#define W_C      8388608u     // xn BF16 [tok][128]; LIVE through k3_conv_enc (fused GEMM!)
#define W_CWT    12582912u    // bf16 conv weights, fragment order [9][8][4][64][8]
#define W_W1T    14680064u    // bf16 w1 FRAGMENT order [4][16 nt][4 kt][64][8]
#define W_W2T    14745600u    // bf16 w2 FRAGMENT order [4][8 nt][8 kt][64][8]
#define W_ENCM   14811136u    // bf16 enc cat-matrix frag order
#define W_DECM   14819328u    // bf16 dec cat-matrix frag order -> ends 14827520
#define W_XMP_RE 14827520u    // x_mean partials [1024 blk][64]
#define W_XMP_IM 14893056u
#define W_EP_RE  14958592u    // |x_out|^2 partials [4096 blk][64]
#define W_EP_IM  15220736u    // ends 15482880
#define W_FLR    15484928u    // flux_seq [16][64]
#define W_FLI    15485952u    // ends 15486976
#define W_EIG_RE 16777216u    // BF16 eig: re elems [0,4.19M), im elems [4.19M,8.39M)
// k1 partials AFTER the bf16 eig region (each 65536 floats)
#define W_K1R    20971520u
#define W_K1I    21037056u
#define W_K1E    21102592u
#define W_SMALL  25165824u
#define W_TE     (W_SMALL+0u)
#define W_MTRE   (W_SMALL+3072u)
#define W_MTIM   (W_SMALL+4096u)
#define W_GATE   (W_SMALL+5120u)
#define W_SRCRE  (W_SMALL+6144u)
#define W_SRCIM  (W_SMALL+7168u)
#define W_OPFRE  (W_SMALL+8192u)
#define W_OPFIM  (W_SMALL+9216u)
#define W_OPDRE  (W_SMALL+10240u)
#define W_OPDIM  (W_SMALL+11264u)
#define W_SCALE  (W_SMALL+12288u)

#define XB_IM 4194304u   // bf16-element offset of im half (xcl, xclbase, eig spaces)

typedef __attribute__((ext_vector_type(8))) short bf16x8;
typedef __attribute__((ext_vector_type(4))) float f32x4;

__device__ __forceinline__ unsigned short bfr(float x) {
  __hip_bfloat16 h = __float2bfloat16(x);
  return *(unsigned short*)&h;
}
__device__ __forceinline__ unsigned int pk2(float a, float b) {
  return ((unsigned int)bfr(b) << 16) | (unsigned int)bfr(a);
}
__device__ __forceinline__ float sb2f(short s) {
  return __uint_as_float(((unsigned int)(unsigned short)s) << 16);
}
__device__ __forceinline__ float softplusf(float x) {
  return (x > 20.f) ? x : log1pf(expf(x));
}
__device__ __forceinline__ float gelu_f(float hv) {
  float z = 1.5957691216f * hv + 0.0713548162f * hv * hv * hv;
  return hv * __builtin_amdgcn_rcpf(1.f + __expf(-z));
}

// K2 v2: stage input; wave-local LN stats + k1 partials (shfl); xn bf16; xclbase bf16.
__global__ __launch_bounds__(256) void k2_transpose_ln(
    const float* __restrict__ xre, const float* __restrict__ xim,
    const float* __restrict__ g, const float* __restrict__ bb_, float* ws) {
  int blk = blockIdx.x; int bt = blk >> 6, h = blk & 63;
  __shared__ float tre[64][65], tim[64][65];
  __shared__ float mean_l[64], rstd_l[64];
  int tid = threadIdx.x;
  size_t inbase = (size_t)bt * 262144 + (size_t)h * 64; // + d*4096 + w
  for (int i = tid; i < 1024; i += 256) {
    int d = i >> 4, w4 = (i & 15) * 4;
    float4 vr = *(const float4*)&xre[inbase + (size_t)d * 4096 + w4];
    float4 vi = *(const float4*)&xim[inbase + (size_t)d * 4096 + w4];
    tre[d][w4] = vr.x; tre[d][w4 + 1] = vr.y; tre[d][w4 + 2] = vr.z; tre[d][w4 + 3] = vr.w;
    tim[d][w4] = vi.x; tim[d][w4 + 1] = vi.y; tim[d][w4 + 2] = vi.z; tim[d][w4 + 3] = vi.w;
  }
  __syncthreads();
  // LN stats: (w = tid>>2, part = tid&3) -> 4 adjacent lanes share w -> shfl reduce
  {
    int w = tid >> 2, part = tid & 3;
    float s = 0.f, sq = 0.f;
    for (int dd = part * 16; dd < part * 16 + 16; dd++) {
      float vr = tre[dd][w], vi = tim[dd][w];
      s += vr + vi; sq += vr * vr + vi * vi;
    }
    s += __shfl_xor(s, 1);  s += __shfl_xor(s, 2);
    sq += __shfl_xor(sq, 1); sq += __shfl_xor(sq, 2);
    if (part == 0) {
      float m = s / 128.f, v = sq / 128.f - m * m;
      mean_l[w] = m; rstd_l[w] = rsqrtf(v + 1e-5f);
    }
  }
  // k1 partials: (d = tid>>2, part = tid&3) shfl reduce -> direct global write
  {
    int d = tid >> 2, part = tid & 3;
    float sr = 0.f, si = 0.f, se = 0.f;
    for (int w2 = part * 16; w2 < part * 16 + 16; w2++) {
      float vr = tre[d][w2], vi = tim[d][w2];
      sr += vr; si += vi; se += vr * vr + vi * vi;
    }
    sr += __shfl_xor(sr, 1); sr += __shfl_xor(sr, 2);
    si += __shfl_xor(si, 1); si += __shfl_xor(si, 2);
    se += __shfl_xor(se, 1); se += __shfl_xor(se, 2);
    if (part == 0) {
      int idx = h * 1024 + bt * 64 + d;
      ws[W_K1R + idx] = sr; ws[W_K1I + idx] = si; ws[W_K1E + idx] = se;
    }
  }
  // xclbase bf16 copy (input layout, w-contiguous)
  {
    __hip_bfloat16* xbb = (__hip_bfloat16*)(ws + W_XB);
    for (int i = tid; i < 1024; i += 256) {
      int d = i >> 4, w4 = (i & 15) * 4;
      size_t ob = (size_t)(bt * 64 + d) * 4096 + (size_t)h * 64 + w4;
      *(unsigned int*)&xbb[ob]     = pk2(tre[d][w4],     tre[d][w4 + 1]);
      *(unsigned int*)&xbb[ob + 2] = pk2(tre[d][w4 + 2], tre[d][w4 + 3]);
      *(unsigned int*)&xbb[XB_IM + ob]     = pk2(tim[d][w4],     tim[d][w4 + 1]);
      *(unsigned int*)&xbb[XB_IM + ob + 2] = pk2(tim[d][w4 + 2], tim[d][w4 + 3]);
    }
  }
  __syncthreads(); // mean_l/rstd_l ready
  size_t tokbase = (size_t)blk * 64;
  __hip_bfloat16* xnb = (__hip_bfloat16*)(ws + W_C);
  int c0 = (tid & 63) * 2, wg = tid >> 6;
  float gc0 = g[c0], bc0 = bb_[c0], gc1 = g[c0 + 1], bc1 = bb_[c0 + 1];
  for (int pass = 0; pass < 16; pass++) {
    int w = pass * 4 + wg;
    float m = mean_l[w], rs = rstd_l[w];
    float v0 = (c0 < 64) ? tre[c0][w] : tim[c0 - 64][w];
    float v1 = (c0 + 1 < 64) ? tre[c0 + 1][w] : tim[c0 + 1 - 64][w];
    *(unsigned int*)&xnb[tokbase * 128 + (size_t)w * 128 + c0] =
        pk2((v0 - m) * rs * gc0 + bc0, (v1 - m) * rs * gc1 + bc1);
  }
}

// K1B2B: finalize k1 partials (momentum in LDS) + mom matmul + advection term; 16 x 128
__global__ void k1b2b(const float* __restrict__ mom_w, const float* __restrict__ mom_b,
                      const float* __restrict__ adv_w, const float* __restrict__ dt, float* ws) {
  int bt = blockIdx.x; int t = bt & 7;
  __shared__ float mc[128], outl[128];
  int tid = threadIdx.x; // 128 threads
  if (tid < 64) {
    int d = tid;
    float a = 0.f, b = 0.f, c = 0.f;
    for (int h = 0; h < 64; h++) {
      int idx = h * 1024 + bt * 64 + d;
      a += ws[W_K1R + idx]; b += ws[W_K1I + idx]; c += ws[W_K1E + idx];
    }
    ws[W_TE + bt * 64 + d] = c / 4096.f;
    mc[d] = a / 4096.f;
    mc[64 + d] = b / 4096.f;
  }
  __syncthreads();
  float acc = mom_b[tid];
  for (int k = 0; k < 128; k++) acc += mc[k] * mom_w[k * 128 + tid];
  outl[tid] = acc;
  __syncthreads();
  if (tid < 64) {
    float f = adv_w[0] * dt[t];
    ws[W_MTRE + bt * 64 + tid] = outl[tid] * f;
    ws[W_MTIM + bt * 64 + tid] = outl[64 + tid] * f;
  }
}

// K0w: bf16 weight prep
__global__ void k0_wprep(const float* __restrict__ w1, const float* __restrict__ w2,
                         const float* __restrict__ cw,
                         const float* __restrict__ enc_re, const float* __restrict__ enc_im,
                         const float* __restrict__ dec_re, const float* __restrict__ dec_im,
                         float* ws) {
  __hip_bfloat16* w1f = (__hip_bfloat16*)(ws + W_W1T);
  __hip_bfloat16* w2f = (__hip_bfloat16*)(ws + W_W2T);
  __hip_bfloat16* cwt = (__hip_bfloat16*)(ws + W_CWT);
  __hip_bfloat16* encM = (__hip_bfloat16*)(ws + W_ENCM);
  __hip_bfloat16* decM = (__hip_bfloat16*)(ws + W_DECM);
  int idx = blockIdx.x * 256 + threadIdx.x; // 0..147455
  if (idx < 131072) {
    {
      int j = idx & 7, lane = (idx >> 3) & 63, kt = (idx >> 9) & 3, nt = (idx >> 11) & 15, e = idx >> 15;
      int cout = nt * 16 + (lane & 15);
      int cin = kt * 32 + (lane >> 4) * 8 + j;
      w1f[idx] = __float2bfloat16(w1[((size_t)(e * 128 + cin)) * 256 + cout]);
    }
    {
      int j = idx & 7, lane = (idx >> 3) & 63, kt = (idx >> 9) & 7, nt = (idx >> 12) & 7, e = idx >> 15;
      int cout = nt * 16 + (lane & 15);
      int cin = kt * 32 + (lane >> 4) * 8 + j;
      w2f[idx] = __float2bfloat16(w2[((size_t)(e * 256 + cin)) * 128 + cout]);
    }
  }
  if (idx < 147456) {
    int j = idx & 7, lane = (idx >> 3) & 63, kt = (idx >> 9) & 3, r = idx >> 11;
    int nt = r & 7, tap = r >> 3;
    int cout = nt * 16 + (lane & 15);
    int cin = kt * 32 + (lane >> 4) * 8 + j;
    cwt[idx] = __float2bfloat16(cw[((size_t)(tap * 128 + cin)) * 128 + cout]);
  }
  if (idx < 16384) {
    int jj = idx & 7, lane = (idx >> 3) & 63, kt = (idx >> 9) & 3, nt = idx >> 11;
    int jc = nt * 16 + (lane & 15);
    int k = kt * 32 + (lane >> 4) * 8 + jj;
    float ve, vd;
    if (k < 64) {
      ve = (jc < 64) ? enc_re[k * 64 + jc] : enc_im[k * 64 + (jc - 64)];
      vd = (jc < 64) ? dec_re[k * 64 + jc] : dec_im[k * 64 + (jc - 64)];
    } else {
      int kk = k - 64;
      ve = (jc < 64) ? -enc_im[kk * 64 + jc] : enc_re[kk * 64 + (jc - 64)];
      vd = (jc < 64) ? -dec_im[kk * 64 + jc] : dec_re[kk * 64 + (jc - 64)];
    }
    encM[idx] = __float2bfloat16(ve);
    decM[idx] = __float2bfloat16(vd);
  }
}

// K3: 3x3 conv (bf16 MFMA); xcl(bf16) = xclbase(bf16) + conv + cb + mom; FUSED enc GEMM.
__global__ __launch_bounds__(256) void k3_conv_enc(const float* __restrict__ cb, float* ws) {
  int blk = blockIdx.x; int bt = blk >> 6, h = blk & 63;
  const __hip_bfloat16* xnb = (const __hip_bfloat16*)(ws + W_C);
  const __hip_bfloat16* cwt = (const __hip_bfloat16*)(ws + W_CWT);
  const __hip_bfloat16* encM = (const __hip_bfloat16*)(ws + W_ENCM);
  const __hip_bfloat16* xbb = (const __hip_bfloat16*)(ws + W_XB);
  __hip_bfloat16* xclb = (__hip_bfloat16*)ws;
  __hip_bfloat16* eigb = (__hip_bfloat16*)(ws + W_EIG_RE);
  __shared__ __align__(16) char smem[3 * 66 * 136 * 2]; // xin; reused as A-tile after conv
  __hip_bfloat16 (*xin)[66][136] = (__hip_bfloat16(*)[66][136])smem;
  char* A = smem; // bf16 [64 rows][256B], XOR-swizzled
  int tid = threadIdx.x, lane = tid & 63, wv = tid >> 6;
  int arow = lane & 15, kgrp = (lane >> 4) * 8, rbase = (lane >> 4) * 4;

  for (int r = 0; r < 3; r++) {
    int hh = h + r - 1;
    if (hh < 0 || hh >= 64) {
      unsigned int* z = (unsigned int*)&xin[r][0][0];
      for (int i = tid; i < 4488; i += 256) z[i] = 0u;
    } else {
      if (tid < 68) *(unsigned int*)&xin[r][0][tid * 2] = 0u;
      else if (tid < 136) *(unsigned int*)&xin[r][65][(tid - 136 + 68) * 2] = 0u;
      const __hip_bfloat16* src = xnb + ((size_t)bt * 4096 + (size_t)hh * 64) * 128;
      for (int i = tid; i < 1024; i += 256) {
        int wp = (i >> 4) + 1, c8 = (i & 15) * 8;
        *(bf16x8*)&xin[r][wp][c8] = *(const bf16x8*)&src[(size_t)(wp - 1) * 128 + c8];
      }
    }
  }
  __syncthreads();

  f32x4 oacc[4][2];
  #pragma unroll
  for (int m = 0; m < 4; m++) {
    oacc[m][0] = (f32x4){0.f, 0.f, 0.f, 0.f};
    oacc[m][1] = (f32x4){0.f, 0.f, 0.f, 0.f};
  }

  for (int tap = 0; tap < 9; tap++) {
    int kh = tap / 3, kw = tap % 3;
    const __hip_bfloat16* wt0 = cwt + ((size_t)(tap * 8 + wv * 2) * 4) * 512 + lane * 8;
    #pragma unroll
    for (int kt = 0; kt < 4; kt++) {
      bf16x8 a[4];
      #pragma unroll
      for (int m = 0; m < 4; m++)
        a[m] = *(const bf16x8*)&xin[kh][m * 16 + arow + kw][kt * 32 + kgrp];
      bf16x8 b0 = *(const bf16x8*)&wt0[(size_t)kt * 512];
      bf16x8 b1 = *(const bf16x8*)&wt0[(size_t)(kt + 4) * 512];
      #pragma unroll
      for (int m = 0; m < 4; m++) {
        oacc[m][0] = __builtin_amdgcn_mfma_f32_16x16x32_bf16(a[m], b0, oacc[m][0], 0, 0, 0);
        oacc[m][1] = __builtin_amdgcn_mfma_f32_16x16x32_bf16(a[m], b1, oacc[m][1], 0, 0, 0);
      }
    }
  }
  __syncthreads(); // xin dead -> A-tile may overwrite

  size_t rowtok = (size_t)blk * 64;
  #pragma unroll
  for (int n = 0; n < 2; n++) {
    int cout = (wv * 2 + n) * 16 + arow;
    bool isre = cout < 64;
    int d = cout & 63;
    float add = cb[cout] + ws[(isre ? W_MTRE : W_MTIM) + bt * 64 + d];
    size_t xb = isre ? 0u : XB_IM;
    const __hip_bfloat16* xsrc = xbb + xb + (size_t)(bt * 64 + d) * 4096 + (size_t)h * 64;
    #pragma unroll
    for (int m = 0; m < 4; m++) {
      unsigned int u0 = *(const unsigned int*)&xsrc[m * 16 + rbase];
      unsigned int u1 = *(const unsigned int*)&xsrc[m * 16 + rbase + 2];
      float xo0 = __uint_as_float(u0 << 16);
      float xo1 = __uint_as_float(u0 & 0xffff0000u);
      float xo2 = __uint_as_float(u1 << 16);
      float xo3 = __uint_as_float(u1 & 0xffff0000u);
      #pragma unroll
      for (int r = 0; r < 4; r++) {
        int w = m * 16 + rbase + r;
        float xo = (r == 0) ? xo0 : (r == 1) ? xo1 : (r == 2) ? xo2 : xo3;
        float v = xo + oacc[m][n][r] + add;
        xclb[xb + (rowtok + w) * 64 + d] = __float2bfloat16(v);
        *(__hip_bfloat16*)(A + w * 256 + ((cout * 2) ^ ((w & 7) << 4))) = __float2bfloat16(v);
      }
    }
  }
  __syncthreads();

  // fused enc GEMM 64x128x128 -> eig (bf16), + x_mean partials (f32)
  f32x4 acc[4][2];
  #pragma unroll
  for (int m = 0; m < 4; m++) {
    acc[m][0] = (f32x4){0.f, 0.f, 0.f, 0.f};
    acc[m][1] = (f32x4){0.f, 0.f, 0.f, 0.f};
  }
  #pragma unroll
  for (int kt = 0; kt < 4; kt++) {
    bf16x8 a[4];
    #pragma unroll
    for (int m = 0; m < 4; m++)
      a[m] = *(const bf16x8*)(A + (m * 16 + arow) * 256 + (((kt * 32 + kgrp) * 2) ^ ((arow & 7) << 4)));
    bf16x8 b0 = *(const bf16x8*)&encM[(((size_t)(wv * 2 + 0) * 4 + kt) * 64 + lane) * 8];
    bf16x8 b1 = *(const bf16x8*)&encM[(((size_t)(wv * 2 + 1) * 4 + kt) * 64 + lane) * 8];
    #pragma unroll
    for (int m = 0; m < 4; m++) {
      acc[m][0] = __builtin_amdgcn_mfma_f32_16x16x32_bf16(a[m], b0, acc[m][0], 0, 0, 0);
      acc[m][1] = __builtin_amdgcn_mfma_f32_16x16x32_bf16(a[m], b1, acc[m][1], 0, 0, 0);
    }
  }
  #pragma unroll
  for (int n = 0; n < 2; n++) {
    int jc = (wv * 2 + n) * 16 + arow;
    size_t eb = (jc < 64) ? 0u : XB_IM;
    int col = jc & 63;
    #pragma unroll
    for (int m = 0; m < 4; m++)
      #pragma unroll
      for (int r = 0; r < 4; r++)
        eigb[eb + (rowtok + m * 16 + rbase + r) * 64 + col] = __float2bfloat16(acc[m][n][r]);
    float s = 0.f;
    #pragma unroll
    for (int m = 0; m < 4; m++)
      #pragma unroll
      for (int r = 0; r < 4; r++) s += acc[m][n][r];
    s += __shfl_xor(s, 16);
    s += __shfl_xor(s, 32);
    if (lane < 16)
      ws[(jc < 64 ? W_XMP_RE : W_XMP_IM) + (size_t)blk * 64 + col] = s;
  }
}

// K6b v2: xm finalize (in LDS) + X_flux matmul + T=8 flux scan; 1 block x 256
__global__ void k6b_flux(const float* __restrict__ fin_re, const float* __restrict__ fin_im,
                         const float* __restrict__ flux_a_re, const float* __restrict__ flux_a_im,
                         float* ws) {
  __shared__ float xmr[1024], xmi[1024], Xfr[1024], Xfi[1024];
  int tid = threadIdx.x;
  for (int i = tid; i < 1024; i += 256) {
    int bt = i >> 6, j = i & 63;
    float sr = 0.f, si = 0.f;
    for (int q = 0; q < 64; q++) {
      sr += ws[W_XMP_RE + (size_t)(bt * 64 + q) * 64 + j];
      si += ws[W_XMP_IM + (size_t)(bt * 64 + q) * 64 + j];
    }
    xmr[i] = sr / 4096.f; xmi[i] = si / 4096.f;
  }
  __syncthreads();
  for (int i = tid; i < 1024; i += 256) {
    int bt = i >> 6, j = i & 63;
    float ar = 0.f, ai = 0.f;
    for (int d = 0; d < 64; d++) {
      float xr = xmr[bt * 64 + d], xi = xmi[bt * 64 + d];
      float wr = fin_re[d * 64 + j], wi = fin_im[d * 64 + j];
      ar += xr * wr - xi * wi; ai += xr * wi + xi * wr;
    }
    Xfr[i] = ar; Xfi[i] = ai;
  }
  __syncthreads();
  if (tid < 128) {
    int b = tid >> 6, j = tid & 63;
    float mag = expf(-softplusf(flux_a_re[j]));
    float aar = mag * cosf(flux_a_im[j]), aai = mag * sinf(flux_a_im[j]);
    float sr = 0.f, si = 0.f;
    for (int t = 0; t < 8; t++) {
      int idx = (b * 8 + t) * 64 + j;
      float nr = aar * sr - aai * si + Xfr[idx];
      float ni = aar * si + aai * sr + Xfi[idx];
      sr = nr; si = ni;
      ws[W_FLR + idx] = sr; ws[W_FLI + idx] = si;
    }
  }
}

// K6c: source/gate/op_decay; 16 blocks (bt) x 256 threads
__global__ void k6c_gate(const float* __restrict__ fproj_re, const float* __restrict__ fproj_im,
                         const float* __restrict__ gate_w, const float* __restrict__ gate_b,
                         const float* __restrict__ lam_re, const float* __restrict__ lam_im,
                         const float* __restrict__ dt, float* ws) {
  int bt = blockIdx.x;
  __shared__ float flr[64], fli[64];
  int tid = threadIdx.x;
  if (tid < 64) { flr[tid] = ws[W_FLR + bt * 64 + tid]; fli[tid] = ws[W_FLI + bt * 64 + tid]; }
  __syncthreads();
  int j = tid >> 2, part = tid & 3;
  float ar = 0.f, ai = 0.f, lg = 0.f;
  for (int d = part * 16; d < part * 16 + 16; d++) {
    float fr = flr[d], fi = fli[d];
    float wr = fproj_re[d * 64 + j], wi = fproj_im[d * 64 + j];
    ar += fr * wr - fi * wi; ai += fr * wi + fi * wr;
    lg += fr * gate_w[d * 64 + j] + fi * gate_w[(64 + d) * 64 + j];
  }
  ar += __shfl_xor(ar, 1); ar += __shfl_xor(ar, 2);
  ai += __shfl_xor(ai, 1); ai += __shfl_xor(ai, 2);
  lg += __shfl_xor(lg, 1); lg += __shfl_xor(lg, 2);
  if (part == 0) {
    int idx = bt * 64 + j;
    ws[W_SRCRE + idx] = ar; ws[W_SRCIM + idx] = ai;
    ws[W_GATE + idx] = 1.f / (1.f + expf(-(lg + gate_b[j])));
  }
  if (tid < 64) {
    int d = tid, t = bt & 7;
    float lr = -softplusf(lam_re[d]), li = lam_im[d];
    float dtv = dt[t];
    float mag = expf(lr * dtv);
    float dr = mag * cosf(li * dtv), di = mag * sinf(li * dtv);
    int idx = bt * 64 + d;
    ws[W_OPDRE + idx] = dr; ws[W_OPDIM + idx] = di;
    float omr = dr - 1.f, omi = di;
    float den = lr * lr + li * li;
    ws[W_OPFRE + idx] = (omr * lr + omi * li) / den;
    ws[W_OPFIM + idx] = (omi * lr - omr * li) / den;
  }
}

// K7_DEC: fused time-scan + dec cgemm + |x_out|^2 partials; u32-paired loads, dbuf A-tile.
__global__ __launch_bounds__(256) void k7_dec(const float* __restrict__ nre,
                                              const float* __restrict__ nim,
                                              const float* __restrict__ dt, float* ws) {
  int blk = blockIdx.x;
  int b = blk >> 8, h = (blk >> 2) & 63, wq = blk & 3;
  const __hip_bfloat16* decM = (const __hip_bfloat16*)(ws + W_DECM);
  __hip_bfloat16* eigb = (__hip_bfloat16*)(ws + W_EIG_RE);
  __shared__ float gl[8][64], srl[8][64], sil[8][64], ofr[8][64], ofi[8][64], odr[8][64], odi[8][64];
  __shared__ __align__(16) char A[2][4096];
  __shared__ float dts[8];
  int tid = threadIdx.x, lane = tid & 63, wv = tid >> 6;
  int arow = lane & 15, kgrp = (lane >> 4) * 8, rbase = (lane >> 4) * 4;
  for (int i = tid; i < 512; i += 256) {
    int t = i >> 6, d = i & 63, idx = (b * 8 + t) * 64 + d;
    gl[t][d]  = ws[W_GATE + idx];
    srl[t][d] = ws[W_SRCRE + idx]; sil[t][d] = ws[W_SRCIM + idx];
    ofr[t][d] = ws[W_OPFRE + idx]; ofi[t][d] = ws[W_OPFIM + idx];
    odr[t][d] = ws[W_OPDRE + idx]; odi[t][d] = ws[W_OPDIM + idx];
  }
  if (tid < 8) dts[tid] = dt[tid];
  __syncthreads();

  int dp = (tid & 31) * 2, wslot = tid >> 5;
  float ur[2][2], ui[2][2];
  #pragma unroll
  for (int a_ = 0; a_ < 2; a_++) { ur[a_][0] = 0.f; ur[a_][1] = 0.f; ui[a_][0] = 0.f; ui[a_][1] = 0.f; }

  for (int t = 0; t < 8; t++) {
    float ns = 0.01f * sqrtf(dts[t]);
    size_t tokb = ((size_t)(b * 8 + t) * 64 + h) * 64 + (size_t)wq * 16;
    char* At = A[t & 1];
    float g0 = gl[t][dp],  g1 = gl[t][dp + 1];
    float s0 = srl[t][dp], s1 = srl[t][dp + 1];
    float q0 = sil[t][dp], q1 = sil[t][dp + 1];
    float f0 = ofr[t][dp], f1 = ofr[t][dp + 1];
    float e0 = ofi[t][dp], e1 = ofi[t][dp + 1];
    float r0 = odr[t][dp], r1 = odr[t][dp + 1];
    float o0 = odi[t][dp], o1 = odi[t][dp + 1];
    #pragma unroll
    for (int wi = 0; wi < 2; wi++) {
      int wl = wslot + wi * 8;
      size_t off = (tokb + wl) * 64 + dp;
      unsigned int re2 = *(const unsigned int*)&eigb[off];
      unsigned int im2 = *(const unsigned int*)&eigb[XB_IM + off];
      float2 nr2 = *(const float2*)&nre[off];
      float2 ni2 = *(const float2*)&nim[off];
      float uo0, vo0, uo1, vo1;
      {
        float er_ = __uint_as_float(re2 << 16);
        float ei_ = __uint_as_float(im2 << 16);
        float fre = er_ * g0 + s0 * (1.f - g0);
        float fim = ei_ * g0 + q0 * (1.f - g0);
        float utr = fre * f0 - fim * e0;
        float uti = fre * e0 + fim * f0;
        float nur = r0 * ur[wi][0] - o0 * ui[wi][0] + utr;
        float nui = r0 * ui[wi][0] + o0 * ur[wi][0] + uti;
        ur[wi][0] = nur; ui[wi][0] = nui;
        uo0 = nur + ns * nr2.x; vo0 = nui + ns * ni2.x;
      }
      {
        float er_ = __uint_as_float(re2 & 0xffff0000u);
        float ei_ = __uint_as_float(im2 & 0xffff0000u);
        float fre = er_ * g1 + s1 * (1.f - g1);
        float fim = ei_ * g1 + q1 * (1.f - g1);
        float utr = fre * f1 - fim * e1;
        float uti = fre * e1 + fim * f1;
        float nur = r1 * ur[wi][1] - o1 * ui[wi][1] + utr;
        float nui = r1 * ui[wi][1] + o1 * ur[wi][1] + uti;
        ur[wi][1] = nur; ui[wi][1] = nui;
        uo1 = nur + ns * nr2.y; vo1 = nui + ns * ni2.y;
      }
      int sw = (wl & 7) << 4;
      *(unsigned int*)(At + wl * 256 + ((dp * 2) ^ sw)) = pk2(uo0, uo1);
      *(unsigned int*)(At + wl * 256 + ((128 + dp * 2) ^ sw)) = pk2(vo0, vo1);
    }
    __syncthreads();
    f32x4 acc[2];
    acc[0] = (f32x4){0.f, 0.f, 0.f, 0.f};
    acc[1] = (f32x4){0.f, 0.f, 0.f, 0.f};
    #pragma unroll
    for (int kt = 0; kt < 4; kt++) {
      bf16x8 a0 = *(const bf16x8*)(At + arow * 256 + (((kt * 32 + kgrp) * 2) ^ ((arow & 7) << 4)));
      bf16x8 b0 = *(const bf16x8*)&decM[(((size_t)(wv * 2 + 0) * 4 + kt) * 64 + lane) * 8];
      bf16x8 b1 = *(const bf16x8*)&decM[(((size_t)(wv * 2 + 1) * 4 + kt) * 64 + lane) * 8];
      acc[0] = __builtin_amdgcn_mfma_f32_16x16x32_bf16(a0, b0, acc[0], 0, 0, 0);
      acc[1] = __builtin_amdgcn_mfma_f32_16x16x32_bf16(a0, b1, acc[1], 0, 0, 0);
    }
    #pragma unroll
    for (int n = 0; n < 2; n++) {
      int jc = (wv * 2 + n) * 16 + arow;
      size_t eb = (jc < 64) ? 0u : XB_IM;
      int col = jc & 63;
      #pragma unroll
      for (int r = 0; r < 4; r++)
        eigb[eb + (tokb + rbase + r) * 64 + col] = __float2bfloat16(acc[n][r]);
      float s = acc[n][0] * acc[n][0] + acc[n][1] * acc[n][1]
              + acc[n][2] * acc[n][2] + acc[n][3] * acc[n][3];
      s += __shfl_xor(s, 16);
      s += __shfl_xor(s, 32);
      if (lane < 16)
        ws[(jc < 64 ? W_EP_RE : W_EP_IM)
           + (size_t)((b * 8 + t) * 256 + h * 4 + wq) * 64 + col] = s;
    }
  }
}

// K9b: combine |x_out|^2 partials -> energy rescale factor per (bt,d)
__global__ void k9b_scale(const float* __restrict__ escale, float* ws) {
  int bt = blockIdx.x; int j = threadIdx.x; // 16 x 64
  float s = 0.f;
  for (int q = 0; q < 256; q++) {
    size_t idx = (size_t)(bt * 256 + q) * 64 + j;
    s += ws[W_EP_RE + idx] + ws[W_EP_IM + idx];
  }
  float cur = s / 4096.f;
  float te = ws[W_TE + bt * 64 + j];
  float ratio = te / (cur + 1e-8f);
  ratio = fminf(fmaxf(ratio, 0.5f), 2.0f);
  ws[W_SCALE + bt * 64 + j] = 1.f + escale[0] * (sqrtf(ratio) - 1.f);
}

// K11 v11: v9 structure (1024x512, per-expert hbufs, 2 barriers) + SWAPPED layer1
// mfma(w1,lt) -> 4 consecutive hid per lane -> 8B gelu LDS writes (4x fewer write instrs).
__global__ __launch_bounds__(512) void k11_moe(
    const float* __restrict__ rw, const float* __restrict__ rb,
    const float* __restrict__ b1, const float* __restrict__ b2,
    const float* __restrict__ g2, const float* __restrict__ b2_,
    float* __restrict__ ws, float* __restrict__ out) {
  int blk = blockIdx.x; int bt = blk >> 6, h = blk & 63;
  const __hip_bfloat16* w1f = (const __hip_bfloat16*)(ws + W_W1T);
  const __hip_bfloat16* w2f = (const __hip_bfloat16*)(ws + W_W2T);
  const __hip_bfloat16* xclb = (const __hip_bfloat16*)ws;
  const __hip_bfloat16* eigb = (const __hip_bfloat16*)(ws + W_EIG_RE);
  // smem: lt [0,16384) | hbuf[e] at 16384 + e*32768, e=0..3  -> 147456 B total
  __shared__ __align__(16) char smem[147456];
  __shared__ float pl[64][4];
  char* lt = smem;
  int tid = threadIdx.x, lane = tid & 63, wv = tid >> 6; // wv in [0,8)
  int arow = lane & 15, kgrp = (lane >> 4) * 8, rbase = (lane >> 4) * 4;
  size_t tokbase = (size_t)blk * 64;

  // ---- phase 1 (barrier-free): LN + router via wave shuffles ----
  int w = tid >> 3, part = tid & 7;
  int c0 = part * 16, dbase = (part & 3) * 16;
  const __hip_bfloat16* rp = eigb + ((part < 4) ? 0u : XB_IM) + (tokbase + w) * 64 + dbase;
  const float* scg = ws + W_SCALE + bt * 64 + dbase;
  float an[16];
  {
    bf16x8 h0 = *(const bf16x8*)rp;
    bf16x8 h1 = *(const bf16x8*)(rp + 8);
    float f[16];
    #pragma unroll
    for (int j = 0; j < 8; j++) {
      f[j]     = sb2f(h0[j]) * scg[j];
      f[8 + j] = sb2f(h1[j]) * scg[8 + j];
    }
    float s = 0.f, sq = 0.f;
    #pragma unroll
    for (int k = 0; k < 16; k++) { s += f[k]; sq += f[k] * f[k]; }
    s  += __shfl_xor(s, 1);  s  += __shfl_xor(s, 2);  s  += __shfl_xor(s, 4);
    sq += __shfl_xor(sq, 1); sq += __shfl_xor(sq, 2); sq += __shfl_xor(sq, 4);
    float m = s / 128.f, v = sq / 128.f - m * m;
    float rstd = rsqrtf(v + 1e-5f);
    int szw = (w & 7) << 4;
    #pragma unroll
    for (int q = 0; q < 4; q++) {
      int c = c0 + q * 4;
      float a0 = (f[q * 4 + 0] - m) * rstd * g2[c]     + b2_[c];
      float a1 = (f[q * 4 + 1] - m) * rstd * g2[c + 1] + b2_[c + 1];
      float a2 = (f[q * 4 + 2] - m) * rstd * g2[c + 2] + b2_[c + 2];
      float a3 = (f[q * 4 + 3] - m) * rstd * g2[c + 3] + b2_[c + 3];
      an[q * 4 + 0] = a0; an[q * 4 + 1] = a1; an[q * 4 + 2] = a2; an[q * 4 + 3] = a3;
      *(unsigned int*)(lt + w * 256 + ((c * 2) ^ szw)) = pk2(a0, a1);
      *(unsigned int*)(lt + w * 256 + (((c + 2) * 2) ^ szw)) = pk2(a2, a3);
    }
    float l0 = 0.f, l1 = 0.f, l2 = 0.f, l3 = 0.f;
    #pragma unroll
    for (int k = 0; k < 16; k++) {
      float4 r4 = *(const float4*)&rw[(c0 + k) * 4];
      l0 += an[k] * r4.x; l1 += an[k] * r4.y; l2 += an[k] * r4.z; l3 += an[k] * r4.w;
    }
    l0 += __shfl_xor(l0, 1); l0 += __shfl_xor(l0, 2); l0 += __shfl_xor(l0, 4);
    l1 += __shfl_xor(l1, 1); l1 += __shfl_xor(l1, 2); l1 += __shfl_xor(l1, 4);
    l2 += __shfl_xor(l2, 1); l2 += __shfl_xor(l2, 2); l2 += __shfl_xor(l2, 4);
    l3 += __shfl_xor(l3, 1); l3 += __shfl_xor(l3, 2); l3 += __shfl_xor(l3, 4);
    l0 += rb[0]; l1 += rb[1]; l2 += rb[2]; l3 += rb[3];
    float mx = fmaxf(fmaxf(l0, l1), fmaxf(l2, l3));
    float e0 = expf(l0 - mx), e1 = expf(l1 - mx), e2 = expf(l2 - mx), e3 = expf(l3 - mx);
    float rs = __builtin_amdgcn_rcpf(e0 + e1 + e2 + e3);
    if (part == 0) {
      float4 p; p.x = e0 * rs; p.y = e1 * rs; p.z = e2 * rs; p.w = e3 * rs;
      *(float4*)&pl[w][0] = p;
    }
  }
  __syncthreads(); // ltok + pl ready

  // out accumulator init = tok residual; wave owns out cols [wv*16, wv*16+16)
  f32x4 oacc[4];
  #pragma unroll
  for (int m = 0; m < 4; m++) {
    int col = wv * 16 + arow;
    oacc[m] = (f32x4){0.f, 0.f, 0.f, 0.f};
    #pragma unroll
    for (int r = 0; r < 4; r++) {
      int row = m * 16 + rbase + r;
      oacc[m][r] = __bfloat162float(
          *(const __hip_bfloat16*)(lt + row * 256 + ((col * 2) ^ ((row & 7) << 4))));
    }
  }

  // ---- layer1 + gelu for ALL experts (barrier-free; per-expert hbuf) ----
  // SWAPPED operands: mfma(w1_frag, lt_frag) -> C: row axis = hid, col (lane) axis = token.
  for (int e = 0; e < 4; e++) {
    char* hb = smem + 16384 + e * 32768;
    f32x4 acc1[4][2]; // [m token-tile][n hid-tile]
    #pragma unroll
    for (int m = 0; m < 4; m++) {
      acc1[m][0] = (f32x4){0.f, 0.f, 0.f, 0.f};
      acc1[m][1] = (f32x4){0.f, 0.f, 0.f, 0.f};
    }
    #pragma unroll
    for (int kt = 0; kt < 4; kt++) {
      bf16x8 a[4];
      #pragma unroll
      for (int m = 0; m < 4; m++) {
        int row = m * 16 + arow;
        a[m] = *(const bf16x8*)(lt + row * 256 + (((kt * 32 + kgrp) * 2) ^ ((arow & 7) << 4)));
      }
      bf16x8 b0 = *(const bf16x8*)&w1f[(((size_t)(e * 16 + wv * 2 + 0) * 4 + kt) * 64 + lane) * 8];
      bf16x8 b1 = *(const bf16x8*)&w1f[(((size_t)(e * 16 + wv * 2 + 1) * 4 + kt) * 64 + lane) * 8];
      #pragma unroll
      for (int m = 0; m < 4; m++) {
        acc1[m][0] = __builtin_amdgcn_mfma_f32_16x16x32_bf16(b0, a[m], acc1[m][0], 0, 0, 0);
        acc1[m][1] = __builtin_amdgcn_mfma_f32_16x16x32_bf16(b1, a[m], acc1[m][1], 0, 0, 0);
      }
    }
    // bias + gelu -> hb [token row][512B hid]: 4 consecutive hid per lane -> one 8B write
    #pragma unroll
    for (int n = 0; n < 2; n++) {
      int hid0 = (wv * 2 + n) * 16 + rbase;
      float4 bv4 = *(const float4*)&b1[e * 256 + hid0];
      #pragma unroll
      for (int m = 0; m < 4; m++) {
        int token = m * 16 + arow;
        unsigned int lo = pk2(gelu_f(acc1[m][n][0] + bv4.x), gelu_f(acc1[m][n][1] + bv4.y));
        unsigned int hi = pk2(gelu_f(acc1[m][n][2] + bv4.z), gelu_f(acc1[m][n][3] + bv4.w));
        int bo = (hid0 * 2) ^ ((token & 7) << 4);
        *(unsigned long long*)(hb + token * 512 + bo) =
            ((unsigned long long)hi << 32) | (unsigned long long)lo;
      }
    }
  }
  __syncthreads(); // ALL hbufs ready

  // ---- layer2 for all experts ----
  for (int e = 0; e < 4; e++) {
    const char* hb = smem + 16384 + e * 32768;
    f32x4 acc2[4];
    #pragma unroll
    for (int m = 0; m < 4; m++) acc2[m] = (f32x4){0.f, 0.f, 0.f, 0.f};
    #pragma unroll
    for (int kt = 0; kt < 8; kt++) {
      bf16x8 a2[4];
      #pragma unroll
      for (int m = 0; m < 4; m++) {
        int row = m * 16 + arow;
        a2[m] = *(const bf16x8*)(hb + row * 512 + (((kt * 32 + kgrp) * 2) ^ ((arow & 7) << 4)));
      }
      bf16x8 bb = *(const bf16x8*)&w2f[(((size_t)(e * 8 + wv) * 8 + kt) * 64 + lane) * 8];
      #pragma unroll
      for (int m = 0; m < 4; m++)
        acc2[m] = __builtin_amdgcn_mfma_f32_16x16x32_bf16(a2[m], bb, acc2[m], 0, 0, 0);
    }
    {
      int col = wv * 16 + arow;
      float bv2 = b2[e * 128 + col];
      #pragma unroll
      for (int m = 0; m < 4; m++)
        #pragma unroll
        for (int r = 0; r < 4; r++)
          oacc[m][r] += pl[m * 16 + rbase + r][e] * (acc2[m][r] + bv2);
    }
  }

  // direct epilogue: residual (bf16 xcl, L2) + float4 stores straight to out
  {
    int col = wv * 16 + arow;
    size_t xb = (col < 64) ? 0u : XB_IM;
    int dd = col & 63;
    size_t obase = (size_t)(col >> 6) * 4194304 + (size_t)bt * 262144
                 + (size_t)dd * 4096 + (size_t)h * 64;
    #pragma unroll
    for (int m = 0; m < 4; m++) {
      int wtb = m * 16 + rbase;
      float4 v;
      #pragma unroll
      for (int r = 0; r < 4; r++) {
        float res = __bfloat162float(xclb[xb + (tokbase + wtb + r) * 64 + dd]);
        ((float*)&v)[r] = oacc[m][r] + res;
      }
      *(float4*)&out[obase + wtb] = v;
    }
  }
}

extern "C" void kernel_launch(void* const* d_in, const int* in_sizes, int n_in,
                              void* d_out, int out_size, void* d_ws, size_t ws_size,
                              hipStream_t stream) {
  const float* x_re      = (const float*)d_in[0];
  const float* x_im      = (const float*)d_in[1];
  const float* dt        = (const float*)d_in[2];
  const float* ln_s_g    = (const float*)d_in[3];
  const float* ln_s_b    = (const float*)d_in[4];
  const float* conv_w    = (const float*)d_in[5];
  const float* conv_b    = (const float*)d_in[6];
  const float* mom_w     = (const float*)d_in[7];
  const float* mom_b     = (const float*)d_in[8];
  const float* adv_w     = (const float*)d_in[9];
  const float* enc_re    = (const float*)d_in[10];
  const float* enc_im    = (const float*)d_in[11];
  const float* dec_re    = (const float*)d_in[12];
  const float* dec_im    = (const float*)d_in[13];
  const float* flux_a_re = (const float*)d_in[14];
  const float* flux_a_im = (const float*)d_in[15];
  const float* fin_re    = (const float*)d_in[16];
  const float* fin_im    = (const float*)d_in[17];
  const float* fproj_re  = (const float*)d_in[18];
  const float* fproj_im  = (const float*)d_in[19];
  const float* gate_w    = (const float*)d_in[20];
  const float* gate_b    = (const float*)d_in[21];
  const float* lam_re    = (const float*)d_in[22];
  const float* lam_im    = (const float*)d_in[23];
  const float* noise_re  = (const float*)d_in[24];
  const float* noise_im  = (const float*)d_in[25];
  const float* e_scale   = (const float*)d_in[26];
  const float* ln_t_g    = (const float*)d_in[27];
  const float* ln_t_b    = (const float*)d_in[28];
  const float* router_w  = (const float*)d_in[29];
  const float* router_b  = (const float*)d_in[30];
  const float* w1        = (const float*)d_in[31];
  const float* b1        = (const float*)d_in[32];
  const float* w2        = (const float*)d_in[33];
  const float* b2        = (const float*)d_in[34];
  float* ws  = (float*)d_ws;
  float* out = (float*)d_out;

  k0_wprep<<<576, 256, 0, stream>>>(w1, w2, conv_w, enc_re, enc_im, dec_re, dec_im, ws);
  k2_transpose_ln<<<1024, 256, 0, stream>>>(x_re, x_im, ln_s_g, ln_s_b, ws);
  k1b2b<<<16, 128, 0, stream>>>(mom_w, mom_b, adv_w, dt, ws);
  k3_conv_enc<<<1024, 256, 0, stream>>>(conv_b, ws);
  k6b_flux<<<1, 256, 0, stream>>>(fin_re, fin_im, flux_a_re, flux_a_im, ws);
  k6c_gate<<<16, 256, 0, stream>>>(fproj_re, fproj_im, gate_w, gate_b, lam_re, lam_im, dt, ws);
  k7_dec<<<512, 256, 0, stream>>>(noise_re, noise_im, dt, ws);
  k9b_scale<<<16, 64, 0, stream>>>(e_scale, ws);
  k11_moe<<<1024, 512, 0, stream>>>(router_w, router_b, b1, b2, ln_t_g, ln_t_b, ws, out);
}